// Round 11
// baseline (264.598 us; speedup 1.0000x reference)
//
#include <hip/hip_runtime.h>
#include <hip/hip_fp16.h>
#include <math.h>

// ---------------------------------------------------------------------------
// GCN 2-layer + two heads, fp32 in/out, MI355X.
//   R16: XCD-local aggregation. The random gather was pinned at ~3.1 TB/s
//   L2-fill (table 12.8MB >> 4MB per-XCD L2). Split each agg over 4 feature
//   quarters; part = blockIdx.x & 3 rides the bid%8 XCD round-robin so each
//   XCD touches ONE 3.2MB slab -> L2-resident gather. Aggs write fp32
//   quarter-rows (exactly one 128B line: no RMW, no cross-XCD line sharing).
//   De-fused: csr+gemm0 | agg0-split | gemm1 | agg1-split | heads.
// ---------------------------------------------------------------------------

#define DFEAT 128
#define BSH 8            // bucket = dst >> 8 (256 nodes/bucket)
#define BKE 4096         // edges per partition block
#define SLABCAP 4608     // bucket slab capacity: mean 4096 + 8 sigma

using half8   = __attribute__((ext_vector_type(8))) _Float16;
using floatx4 = __attribute__((ext_vector_type(4))) float;

__device__ __forceinline__ void split_f16(float x, _Float16& hi, _Float16& lo) {
    _Float16 h = (_Float16)x;
    hi = h;
    lo = (_Float16)(x - (float)h);
}

// ---------------- K1: W pre-split to f16 frags  +  slab partition -----------
__global__ __launch_bounds__(256) void prep_part_k(const int* __restrict__ src,
                                                   const int* __restrict__ dst,
                                                   int* __restrict__ cursor,
                                                   unsigned* __restrict__ pk_out,
                                                   const float* __restrict__ W0,
                                                   const float* __restrict__ W1,
                                                   const float* __restrict__ W2,
                                                   const float* __restrict__ W3,
                                                   _Float16* __restrict__ hi_all,
                                                   _Float16* __restrict__ lo_all,
                                                   int E, int nbuk) {
    int tid = threadIdx.x;
    if (blockIdx.x < 256) {
        int pb = blockIdx.x;
        int b = pb >> 6;
        const float* W = (b == 0) ? W0 : (b == 1) ? W1 : (b == 2) ? W2 : W3;
        _Float16* hi = hi_all + (size_t)b * 16384;
        _Float16* lo = lo_all + (size_t)b * 16384;
        int i = (pb & 63) * 256 + tid;
        int j = i & 7;
        int lane = (i >> 3) & 63;
        int ts = i >> 9;
        int s = ts & 3, t = ts >> 2;
        int k = s * 32 + (lane >> 4) * 8 + j;
        int n = t * 16 + (lane & 15);
        split_f16(W[k * 128 + n], hi[i], lo[i]);
        return;
    }

    // ---- partition body ----
    __shared__ int h[256];
    __shared__ int base[256];
    h[tid] = 0;
    __syncthreads();
    int B = blockIdx.x - 256;
    int e0 = B * BKE;

    unsigned pk[16];
    unsigned short rk[16];
    unsigned char bk[16];
    int m = 0;
#pragma unroll
    for (int it = 0; it < 4; ++it) {
        int e = e0 + it * 1024 + tid * 4;
        if (e + 3 < E) {
            int4 d4 = *(const int4*)(dst + e);
            int4 s4 = *(const int4*)(src + e);
            int dd[4] = {d4.x, d4.y, d4.z, d4.w};
            int ss[4] = {s4.x, s4.y, s4.z, s4.w};
#pragma unroll
            for (int k = 0; k < 4; ++k) {
                int b = dd[k] >> BSH;
                pk[m] = ((unsigned)dd[k] << 16) | (unsigned)ss[k];
                rk[m] = (unsigned short)atomicAdd(&h[b], 1);
                bk[m] = (unsigned char)b;
                ++m;
            }
        } else {
            for (int k = 0; k < 4; ++k) {
                if (e + k < E) {
                    int d = dst[e + k], sv = src[e + k];
                    int b = d >> BSH;
                    pk[m] = ((unsigned)d << 16) | (unsigned)sv;
                    rk[m] = (unsigned short)atomicAdd(&h[b], 1);
                    bk[m] = (unsigned char)b;
                    ++m;
                }
            }
        }
    }
    __syncthreads();
    if (tid < nbuk && h[tid]) base[tid] = tid * SLABCAP + atomicAdd(&cursor[tid], h[tid]);
    __syncthreads();
    for (int j2 = 0; j2 < m; ++j2)
        pk_out[base[bk[j2]] + (int)rk[j2]] = pk[j2];
}

// ---------------- CSR build from slabs (counts live in cursor) --------------
__device__ __forceinline__ void csr_body(const unsigned* __restrict__ pk_arr,
                                         const int* __restrict__ cursor,
                                         int* __restrict__ row_ptr,
                                         unsigned short* __restrict__ col_idx,
                                         float* __restrict__ dinv,
                                         int N, int E, int nbuk, int b) {
    __shared__ int hcnt[256];
    __shared__ int esc[256];
    __shared__ int sx[256];
    int tid = threadIdx.x;

    int v = (tid < nbuk) ? cursor[tid] : 0;
    sx[tid] = v;
    __syncthreads();
    int x = v;
    for (int o = 1; o < 256; o <<= 1) {
        int y = (tid >= o) ? sx[tid - o] : 0;
        __syncthreads();
        x += y;
        sx[tid] = x;
        __syncthreads();
    }
    int s0 = (b > 0) ? sx[b - 1] : 0;
    int cnt = sx[b] - s0;
    __syncthreads();

    hcnt[tid] = 0;
    __syncthreads();

    const unsigned* slab = pk_arr + (size_t)b * SLABCAP;
    unsigned p[20];
    unsigned short r[20];
    int m = 0;
    for (int i = tid; i < cnt; i += 256) {
        unsigned pp = slab[i];
        int d = (pp >> 16) & 255;
        r[m] = (unsigned short)atomicAdd(&hcnt[d], 1);
        p[m] = pp;
        ++m;
    }
    __syncthreads();

    int hv = hcnt[tid];
    esc[tid] = hv;
    __syncthreads();
    int hx = hv;
    for (int o = 1; o < 256; o <<= 1) {
        int y = (tid >= o) ? esc[tid - o] : 0;
        __syncthreads();
        hx += y;
        esc[tid] = hx;
        __syncthreads();
    }
    int excl = hx - hv;
    __syncthreads();
    esc[tid] = excl;
    __syncthreads();

    int node = (b << BSH) + tid;
    if (node < N) {
        row_ptr[node] = s0 + excl;
        dinv[node] = rsqrtf((float)(hv + 1));   // +1 self loop
    }
    if (node == N) row_ptr[N] = E;

    for (int j = 0; j < m; ++j) {
        int d = (p[j] >> 16) & 255;
        col_idx[s0 + esc[d] + (int)r[j]] = (unsigned short)(p[j] & 0xFFFFu);
    }
}

// ---------------- GEMM pieces (split-f16 MFMA, prepped fragments) -----------
__device__ __forceinline__ void stage_frags(const _Float16* __restrict__ Whi,
                                            const _Float16* __restrict__ Wlo,
                                            _Float16* __restrict__ WhiS,
                                            _Float16* __restrict__ WloS) {
    const int tid = threadIdx.x;
#pragma unroll
    for (int j = 0; j < 8; ++j)
        ((float4*)WhiS)[tid + j * 256] = ((const float4*)Whi)[tid + j * 256];
#pragma unroll
    for (int j = 0; j < 8; ++j)
        ((float4*)WloS)[tid + j * 256] = ((const float4*)Wlo)[tid + j * 256];
}

__device__ __forceinline__ void load_A_f32(const float* __restrict__ X, int M, int m0,
                                           half8 (&Ahi)[2][4], half8 (&Alo)[2][4]) {
    const int lane = threadIdx.x & 63;
    const int quad = lane >> 4, l16 = lane & 15;
#pragma unroll
    for (int r = 0; r < 2; ++r) {
        int row = m0 + r * 16 + l16;
        row = row < M ? row : (M - 1);
        const float* xr = X + (size_t)row * 128 + quad * 8;
#pragma unroll
        for (int s = 0; s < 4; ++s) {
            float4 a = ((const float4*)(xr + s * 32))[0];
            float4 b = ((const float4*)(xr + s * 32))[1];
            float v[8] = {a.x, a.y, a.z, a.w, b.x, b.y, b.z, b.w};
#pragma unroll
            for (int j = 0; j < 8; ++j) {
                _Float16 hi, lo;
                split_f16(v[j], hi, lo);
                Ahi[r][s][j] = hi;
                Alo[r][s][j] = lo;
            }
        }
    }
}

// Shared GEMM body: fp32 input, 3-term split-f16 MFMA, full-line fp16 output
// epilogue staged through SMEM (no partial-line write-allocate RMW).
__device__ __forceinline__ void gemm_body(const float* __restrict__ X,
                                          const _Float16* __restrict__ Whi,
                                          const _Float16* __restrict__ Wlo,
                                          __half* __restrict__ Y,
                                          int M, int blk, _Float16* SMEM) {
    _Float16* WhiS = SMEM;
    _Float16* WloS = SMEM + 16384;
    stage_frags(Whi, Wlo, WhiS, WloS);
    half8 Ahi[2][4], Alo[2][4];
    const int tid = threadIdx.x;
    const int lane = tid & 63, wave = tid >> 6;
    const int quad = lane >> 4, l16 = lane & 15;
    int m0 = blk * 128 + wave * 32;
    load_A_f32(X, M, m0, Ahi, Alo);
    __syncthreads();

    floatx4 acc[2][8];
#pragma unroll
    for (int r = 0; r < 2; ++r)
#pragma unroll
        for (int t = 0; t < 8; ++t) acc[r][t] = (floatx4){0.f, 0.f, 0.f, 0.f};

    const half8* WH = (const half8*)WhiS;
    const half8* WL = (const half8*)WloS;
#pragma unroll
    for (int s = 0; s < 4; ++s) {
#pragma unroll
        for (int t = 0; t < 8; ++t) {
            half8 bh = WH[(t * 4 + s) * 64 + lane];
            half8 bl = WL[(t * 4 + s) * 64 + lane];
#pragma unroll
            for (int r = 0; r < 2; ++r) {
                acc[r][t] = __builtin_amdgcn_mfma_f32_16x16x32_f16(Ahi[r][s], bh, acc[r][t], 0, 0, 0);
                acc[r][t] = __builtin_amdgcn_mfma_f32_16x16x32_f16(Alo[r][s], bh, acc[r][t], 0, 0, 0);
                acc[r][t] = __builtin_amdgcn_mfma_f32_16x16x32_f16(Ahi[r][s], bl, acc[r][t], 0, 0, 0);
            }
        }
    }

    __syncthreads();   // all W-fragment reads done; SMEM reusable
#pragma unroll
    for (int r = 0; r < 2; ++r)
#pragma unroll
        for (int t = 0; t < 8; ++t)
#pragma unroll
            for (int e = 0; e < 4; ++e)
                SMEM[(wave * 32 + r * 16 + quad * 4 + e) * 136 + t * 16 + l16] =
                    (_Float16)acc[r][t][e];
    __syncthreads();
#pragma unroll
    for (int it = 0; it < 8; ++it) {
        int lr = it * 16 + (tid >> 4);
        int grow = blk * 128 + lr;
        if (grow < M)
            *(uint4*)(Y + (size_t)grow * 128 + (tid & 15) * 8) =
                *(const uint4*)(&SMEM[lr * 136 + (tid & 15) * 8]);
    }
}

// ---------------- K2: fused CSR build + layer-0 GEMM ------------------------
__global__ __launch_bounds__(256) void csrgemm_k(const unsigned* __restrict__ pk_arr,
                                                 const int* __restrict__ cursor,
                                                 int* __restrict__ row_ptr,
                                                 unsigned short* __restrict__ col_idx,
                                                 float* __restrict__ dinv,
                                                 const float* __restrict__ X,
                                                 const _Float16* __restrict__ Whi,
                                                 const _Float16* __restrict__ Wlo,
                                                 __half* __restrict__ hs,
                                                 int N, int E, int nbuk) {
    if ((int)blockIdx.x < nbuk) {
        csr_body(pk_arr, cursor, row_ptr, col_idx, dinv, N, E, nbuk, blockIdx.x);
        return;
    }
    __shared__ _Float16 SMEM[32768];
    gemm_body(X, Whi, Wlo, hs, N, blockIdx.x - nbuk, SMEM);
}

// ---------------- K4: standalone layer-1 GEMM -------------------------------
__global__ __launch_bounds__(256) void gemm1_k(const float* __restrict__ X,
                                               const _Float16* __restrict__ Whi,
                                               const _Float16* __restrict__ Wlo,
                                               __half* __restrict__ Y, int N) {
    __shared__ _Float16 SMEM[32768];
    gemm_body(X, Whi, Wlo, Y, N, blockIdx.x, SMEM);
}

// ---------------- K3/K5: XCD-local feature-split aggregate ------------------
// part = blockIdx.x & 3 -> via bid%8 XCD round-robin, XCD k always sees part
// k&3: its gather slab is 3.2MB (quarter of the fp16 table) -> L2-resident.
// 8-lane groups, one node each; uint2 (8B) gathers; fp32 quarter-row output
// = exactly one 128B line (no RMW, no cross-XCD partial-line hazard).
template <bool WEIGHTED>
__global__ __launch_bounds__(256, 8) void agg_split_k(const __half* __restrict__ tab,
                                                      const int* __restrict__ row_ptr,
                                                      const unsigned short* __restrict__ col_idx,
                                                      const float* __restrict__ dinv,
                                                      const float* __restrict__ bias,
                                                      float* __restrict__ outp, int n) {
    const int tid = threadIdx.x;
    const int c8 = tid & 7;
    const int gw = tid & 56;           // 8-lane group base within wave
    const int part = blockIdx.x & 3;
    const int chunk = blockIdx.x >> 2;
    int i = chunk * 32 + (tid >> 3);
    if (i >= n) return;

    const int coff = part * 32 + c8 * 4;   // half-elements into the row

    float di = dinv[i];
    float acc[4];
    {
        uint2 raw = *(const uint2*)(tab + (size_t)i * DFEAT + coff);
        const __half2* hp = (const __half2*)&raw;
        float2 f0 = __half22float2(hp[0]);
        float2 f1 = __half22float2(hp[1]);
        if (WEIGHTED) {
            acc[0] = f0.x * di; acc[1] = f0.y * di;
            acc[2] = f1.x * di; acc[3] = f1.y * di;
        } else {
            acc[0] = f0.x; acc[1] = f0.y; acc[2] = f1.x; acc[3] = f1.y;
        }
    }

    int s = row_ptr[i];
    int cnt = row_ptr[i + 1] - s;

    for (int base = 0; base < cnt; base += 8) {
        int t = base + c8;
        int idx = (t < cnt) ? (int)col_idx[s + t] : 0;
        float dv = 0.f;
        if (WEIGHTED) dv = (t < cnt) ? dinv[idx] : 0.f;
        int lim = cnt - base; if (lim > 8) lim = 8;
        uint2 vv[8];
#pragma unroll
        for (int q = 0; q < 8; ++q) {
            int ia = __shfl(idx, gw + q);
            if (q < lim)
                vv[q] = *(const uint2*)(tab + (size_t)ia * DFEAT + coff);
        }
#pragma unroll
        for (int q = 0; q < 8; ++q) {
            if (q < lim) {
                const __half2* pq = (const __half2*)&vv[q];
                float2 f0 = __half22float2(pq[0]);
                float2 f1 = __half22float2(pq[1]);
                if (WEIGHTED) {
                    float wq = __shfl(dv, gw + q);
                    acc[0] = fmaf(f0.x, wq, acc[0]);
                    acc[1] = fmaf(f0.y, wq, acc[1]);
                    acc[2] = fmaf(f1.x, wq, acc[2]);
                    acc[3] = fmaf(f1.y, wq, acc[3]);
                } else {
                    acc[0] += f0.x; acc[1] += f0.y;
                    acc[2] += f1.x; acc[3] += f1.y;
                }
            }
        }
    }

    float4 bq = *(const float4*)(bias + coff);
    float o0 = fmaf(acc[0], di, bq.x);
    float o1 = fmaf(acc[1], di, bq.y);
    float o2 = fmaf(acc[2], di, bq.z);
    float o3 = fmaf(acc[3], di, bq.w);
    if (WEIGHTED) {     // h1' = di * relu(.)  (pre-scaled for layer-1 GEMM)
        o0 = fmaxf(o0, 0.f) * di; o1 = fmaxf(o1, 0.f) * di;
        o2 = fmaxf(o2, 0.f) * di; o3 = fmaxf(o3, 0.f) * di;
    }
    *(float4*)(outp + (size_t)i * DFEAT + coff) = make_float4(o0, o1, o2, o3);
}

// ---------------- K6: heads (32 rows/block, LDS A-tiles, staged output) -----
#define LPH 136   // f16 LDS row stride
#define LPO 132   // f32 out-stage row stride
__global__ __launch_bounds__(256, 4) void heads_k(const float* __restrict__ X,
                                                  const _Float16* __restrict__ WvHi,
                                                  const _Float16* __restrict__ WvLo,
                                                  const _Float16* __restrict__ WtHi,
                                                  const _Float16* __restrict__ WtLo,
                                                  const float* __restrict__ bv,
                                                  const float* __restrict__ bt,
                                                  float* __restrict__ out_v,
                                                  float* __restrict__ out_t, int n) {
    __shared__ _Float16 AHi[32 * LPH];
    __shared__ _Float16 ALo[32 * LPH];
    __shared__ float OS[32 * LPO];
    const int tid = threadIdx.x;

    // load 32 rows of X, split to f16 hi/lo LDS tiles
    {
        int r = tid >> 3, c0 = (tid & 7) * 16;
        int grow = blockIdx.x * 32 + r;
        int gr = grow < n ? grow : (n > 0 ? n - 1 : 0);
#pragma unroll
        for (int q = 0; q < 4; ++q) {
            float4 v = *(const float4*)(X + (size_t)gr * DFEAT + c0 + q * 4);
            float vs[4] = {v.x, v.y, v.z, v.w};
#pragma unroll
            for (int e = 0; e < 4; ++e) {
                _Float16 hi, lo;
                split_f16(vs[e], hi, lo);
                AHi[r * LPH + c0 + q * 4 + e] = hi;
                ALo[r * LPH + c0 + q * 4 + e] = lo;
            }
        }
    }
    __syncthreads();

    const int lane = tid & 63, wave = tid >> 6;
    const int quad = lane >> 4, l16 = lane & 15;

#pragma unroll
    for (int hd = 0; hd < 2; ++hd) {
        const _Float16* Hi = hd ? WtHi : WvHi;
        const _Float16* Lo = hd ? WtLo : WvLo;
        const float* bb    = hd ? bt : bv;
        float* outp        = hd ? out_t : out_v;

        floatx4 acc[2][2];
#pragma unroll
        for (int tile = 0; tile < 2; ++tile) {
            acc[tile][0] = (floatx4){0.f, 0.f, 0.f, 0.f};
            acc[tile][1] = (floatx4){0.f, 0.f, 0.f, 0.f};
        }
#pragma unroll
        for (int s = 0; s < 4; ++s) {
#pragma unroll
            for (int tt = 0; tt < 2; ++tt) {
                size_t fi = ((size_t)(((wave * 2 + tt) * 4 + s) * 64 + lane)) * 8;
                half8 bh = *(const half8*)(Hi + fi);
                half8 bl = *(const half8*)(Lo + fi);
#pragma unroll
                for (int tile = 0; tile < 2; ++tile) {
                    int al = (tile * 16 + l16) * LPH + s * 32 + quad * 8;
                    half8 ahi = *(const half8*)(&AHi[al]);
                    half8 alo = *(const half8*)(&ALo[al]);
                    acc[tile][tt] = __builtin_amdgcn_mfma_f32_16x16x32_f16(ahi, bh, acc[tile][tt], 0, 0, 0);
                    acc[tile][tt] = __builtin_amdgcn_mfma_f32_16x16x32_f16(alo, bh, acc[tile][tt], 0, 0, 0);
                    acc[tile][tt] = __builtin_amdgcn_mfma_f32_16x16x32_f16(ahi, bl, acc[tile][tt], 0, 0, 0);
                }
            }
        }
        // stage into OS, then full 512B row stores
#pragma unroll
        for (int tile = 0; tile < 2; ++tile) {
#pragma unroll
            for (int tt = 0; tt < 2; ++tt) {
                int col = (wave * 2 + tt) * 16 + l16;
                float bc = bb[col];
#pragma unroll
                for (int e = 0; e < 4; ++e)
                    OS[(tile * 16 + quad * 4 + e) * LPO + col] =
                        fmaxf(acc[tile][tt][e] + bc, 0.f);
            }
        }
        __syncthreads();
        {
            int r = tid >> 3, c0 = (tid & 7) * 16;
            int grow = blockIdx.x * 32 + r;
            if (grow < n) {
#pragma unroll
                for (int q = 0; q < 4; ++q)
                    *(float4*)(outp + (size_t)grow * DFEAT + c0 + q * 4) =
                        *(const float4*)(&OS[r * LPO + c0 + q * 4]);
            }
        }
        __syncthreads();
    }
}

// ---------------------------------------------------------------------------

static inline size_t align_up(size_t x, size_t a) { return (x + a - 1) & ~(a - 1); }

extern "C" void kernel_launch(void* const* d_in, const int* in_sizes, int n_in,
                              void* d_out, int out_size, void* d_ws, size_t ws_size,
                              hipStream_t stream) {
    const float* x  = (const float*)d_in[0];
    const int*   ei = (const int*)d_in[1];
    const float* W0 = (const float*)d_in[2];
    const float* b0 = (const float*)d_in[3];
    const float* W1 = (const float*)d_in[4];
    const float* b1 = (const float*)d_in[5];
    const float* Wv = (const float*)d_in[6];
    const float* bv = (const float*)d_in[7];
    const float* Wt = (const float*)d_in[8];
    const float* bt = (const float*)d_in[9];

    const int N = in_sizes[0] / DFEAT;
    const int E = in_sizes[1] / 2;
    const int* src = ei;
    const int* dst = ei + E;
    const int nbuk = (N + 255) >> BSH;
    const int npb  = (E + BKE - 1) / BKE;
    const int gb   = (N + 127) / 128;
    const int nchk = (N + 31) / 32;

    // workspace carve-up
    char* w = (char*)d_ws;
    int* cursor      = (int*)w; w += align_up((size_t)256 * 4, 256);
    unsigned* pk_arr = (unsigned*)w; w += align_up((size_t)nbuk * SLABCAP * 4, 256);
    int* row_ptr     = (int*)w; w += align_up((size_t)(N + 1) * 4, 256);
    unsigned short* col_idx = (unsigned short*)w; w += align_up((size_t)E * 2, 256);
    float* dinv      = (float*)w; w += align_up((size_t)N * 4, 256);
    _Float16* whi_all = (_Float16*)w; w += align_up(4 * 16384 * 2, 256);
    _Float16* wlo_all = (_Float16*)w; w += align_up(4 * 16384 * 2, 256);
    __half* hs       = (__half*)w; w += align_up((size_t)N * DFEAT * 2, 256);
    __half* hs2      = (__half*)w; w += align_up((size_t)N * DFEAT * 2, 256);
    float* h1p       = (float*)w; w += align_up((size_t)N * DFEAT * 4, 256);

    _Float16* w0hi = whi_all;            _Float16* w0lo = wlo_all;
    _Float16* w1hi = whi_all + 16384;    _Float16* w1lo = wlo_all + 16384;
    _Float16* wvhi = whi_all + 2*16384;  _Float16* wvlo = wlo_all + 2*16384;
    _Float16* wthi = whi_all + 3*16384;  _Float16* wtlo = wlo_all + 3*16384;

    float* out_h = (float*)d_out;
    float* out_v = out_h + (size_t)N * DFEAT;
    float* out_t = out_h + 2 * (size_t)N * DFEAT;

    hipMemsetAsync(cursor, 0, 256 * 4, stream);

    // K1: W prep + slab partition
    prep_part_k<<<256 + npb, 256, 0, stream>>>(src, dst, cursor, pk_arr,
                                               W0, W1, Wv, Wt, whi_all, wlo_all,
                                               E, nbuk);
    // K2: CSR build + layer-0 GEMM (co-resident) -> hs (fp16, full rows)
    csrgemm_k<<<nbuk + gb, 256, 0, stream>>>(pk_arr, cursor, row_ptr, col_idx,
                                             dinv, x, w0hi, w0lo, hs, N, E, nbuk);
    // K3: weighted agg, XCD-local feature quarters -> h1p (fp32)
    agg_split_k<true><<<nchk * 4, 256, 0, stream>>>(hs, row_ptr, col_idx, dinv,
                                                    b0, h1p, N);
    // K4: layer-1 GEMM -> hs2 (fp16, rows auto-scaled via pre-scaled h1p)
    gemm1_k<<<gb, 256, 0, stream>>>(h1p, w1hi, w1lo, hs2, N);
    // K5: plain agg, XCD-local feature quarters -> out_h (fp32)
    agg_split_k<false><<<nchk * 4, 256, 0, stream>>>(hs2, row_ptr, col_idx, dinv,
                                                     b1, out_h, N);
    // K6: heads from out_h
    heads_k<<<nchk, 256, 0, stream>>>(out_h, wvhi, wvlo, wthi, wtlo, bv, bt,
                                      out_v, out_t, N);
}

// Round 12
// 243.245 us; speedup vs baseline: 1.0878x; 1.0878x over previous
//
#include <hip/hip_runtime.h>
#include <hip/hip_fp16.h>
#include <math.h>

// ---------------------------------------------------------------------------
// GCN 2-layer + two heads, fp32 in/out, MI355X.
//   R17: XCD-local aggregation, take 2. R16 failed because part slabs were
//   STRIDED (64B slivers in 256B rows -> 6.4MB line footprint > 4MB L2,
//   FETCH rose 84->105MB). Now the gather tables are PART-MAJOR: 4 contiguous
//   [N][32] fp16 slabs (3.2MB each, 64B/node-row). part = bid&3 rides the
//   bid%8 XCD round-robin -> each XCD's gather slab is L2-resident.
//   GEMM epilogues write quarter-rows into the 4 slabs (full-line coverage);
//   agg outputs stay standard layout (32 fp32 per part = one 128B line).
// ---------------------------------------------------------------------------

#define DFEAT 128
#define BSH 8            // bucket = dst >> 8 (256 nodes/bucket)
#define BKE 4096         // edges per partition block
#define SLABCAP 4608     // bucket slab capacity: mean 4096 + 8 sigma

using half8   = __attribute__((ext_vector_type(8))) _Float16;
using floatx4 = __attribute__((ext_vector_type(4))) float;

__device__ __forceinline__ void split_f16(float x, _Float16& hi, _Float16& lo) {
    _Float16 h = (_Float16)x;
    hi = h;
    lo = (_Float16)(x - (float)h);
}

// ---------------- K1: W pre-split to f16 frags  +  slab partition -----------
__global__ __launch_bounds__(256) void prep_part_k(const int* __restrict__ src,
                                                   const int* __restrict__ dst,
                                                   int* __restrict__ cursor,
                                                   unsigned* __restrict__ pk_out,
                                                   const float* __restrict__ W0,
                                                   const float* __restrict__ W1,
                                                   const float* __restrict__ W2,
                                                   const float* __restrict__ W3,
                                                   _Float16* __restrict__ hi_all,
                                                   _Float16* __restrict__ lo_all,
                                                   int E, int nbuk) {
    int tid = threadIdx.x;
    if (blockIdx.x < 256) {
        int pb = blockIdx.x;
        int b = pb >> 6;
        const float* W = (b == 0) ? W0 : (b == 1) ? W1 : (b == 2) ? W2 : W3;
        _Float16* hi = hi_all + (size_t)b * 16384;
        _Float16* lo = lo_all + (size_t)b * 16384;
        int i = (pb & 63) * 256 + tid;
        int j = i & 7;
        int lane = (i >> 3) & 63;
        int ts = i >> 9;
        int s = ts & 3, t = ts >> 2;
        int k = s * 32 + (lane >> 4) * 8 + j;
        int n = t * 16 + (lane & 15);
        split_f16(W[k * 128 + n], hi[i], lo[i]);
        return;
    }

    // ---- partition body ----
    __shared__ int h[256];
    __shared__ int base[256];
    h[tid] = 0;
    __syncthreads();
    int B = blockIdx.x - 256;
    int e0 = B * BKE;

    unsigned pk[16];
    unsigned short rk[16];
    unsigned char bk[16];
    int m = 0;
#pragma unroll
    for (int it = 0; it < 4; ++it) {
        int e = e0 + it * 1024 + tid * 4;
        if (e + 3 < E) {
            int4 d4 = *(const int4*)(dst + e);
            int4 s4 = *(const int4*)(src + e);
            int dd[4] = {d4.x, d4.y, d4.z, d4.w};
            int ss[4] = {s4.x, s4.y, s4.z, s4.w};
#pragma unroll
            for (int k = 0; k < 4; ++k) {
                int b = dd[k] >> BSH;
                pk[m] = ((unsigned)dd[k] << 16) | (unsigned)ss[k];
                rk[m] = (unsigned short)atomicAdd(&h[b], 1);
                bk[m] = (unsigned char)b;
                ++m;
            }
        } else {
            for (int k = 0; k < 4; ++k) {
                if (e + k < E) {
                    int d = dst[e + k], sv = src[e + k];
                    int b = d >> BSH;
                    pk[m] = ((unsigned)d << 16) | (unsigned)sv;
                    rk[m] = (unsigned short)atomicAdd(&h[b], 1);
                    bk[m] = (unsigned char)b;
                    ++m;
                }
            }
        }
    }
    __syncthreads();
    if (tid < nbuk && h[tid]) base[tid] = tid * SLABCAP + atomicAdd(&cursor[tid], h[tid]);
    __syncthreads();
    for (int j2 = 0; j2 < m; ++j2)
        pk_out[base[bk[j2]] + (int)rk[j2]] = pk[j2];
}

// ---------------- CSR build from slabs (counts live in cursor) --------------
__device__ __forceinline__ void csr_body(const unsigned* __restrict__ pk_arr,
                                         const int* __restrict__ cursor,
                                         int* __restrict__ row_ptr,
                                         unsigned short* __restrict__ col_idx,
                                         float* __restrict__ dinv,
                                         int N, int E, int nbuk, int b) {
    __shared__ int hcnt[256];
    __shared__ int esc[256];
    __shared__ int sx[256];
    int tid = threadIdx.x;

    int v = (tid < nbuk) ? cursor[tid] : 0;
    sx[tid] = v;
    __syncthreads();
    int x = v;
    for (int o = 1; o < 256; o <<= 1) {
        int y = (tid >= o) ? sx[tid - o] : 0;
        __syncthreads();
        x += y;
        sx[tid] = x;
        __syncthreads();
    }
    int s0 = (b > 0) ? sx[b - 1] : 0;
    int cnt = sx[b] - s0;
    __syncthreads();

    hcnt[tid] = 0;
    __syncthreads();

    const unsigned* slab = pk_arr + (size_t)b * SLABCAP;
    unsigned p[20];
    unsigned short r[20];
    int m = 0;
    for (int i = tid; i < cnt; i += 256) {
        unsigned pp = slab[i];
        int d = (pp >> 16) & 255;
        r[m] = (unsigned short)atomicAdd(&hcnt[d], 1);
        p[m] = pp;
        ++m;
    }
    __syncthreads();

    int hv = hcnt[tid];
    esc[tid] = hv;
    __syncthreads();
    int hx = hv;
    for (int o = 1; o < 256; o <<= 1) {
        int y = (tid >= o) ? esc[tid - o] : 0;
        __syncthreads();
        hx += y;
        esc[tid] = hx;
        __syncthreads();
    }
    int excl = hx - hv;
    __syncthreads();
    esc[tid] = excl;
    __syncthreads();

    int node = (b << BSH) + tid;
    if (node < N) {
        row_ptr[node] = s0 + excl;
        dinv[node] = rsqrtf((float)(hv + 1));   // +1 self loop
    }
    if (node == N) row_ptr[N] = E;

    for (int j = 0; j < m; ++j) {
        int d = (p[j] >> 16) & 255;
        col_idx[s0 + esc[d] + (int)r[j]] = (unsigned short)(p[j] & 0xFFFFu);
    }
}

// ---------------- GEMM pieces (split-f16 MFMA, prepped fragments) -----------
__device__ __forceinline__ void stage_frags(const _Float16* __restrict__ Whi,
                                            const _Float16* __restrict__ Wlo,
                                            _Float16* __restrict__ WhiS,
                                            _Float16* __restrict__ WloS) {
    const int tid = threadIdx.x;
#pragma unroll
    for (int j = 0; j < 8; ++j)
        ((float4*)WhiS)[tid + j * 256] = ((const float4*)Whi)[tid + j * 256];
#pragma unroll
    for (int j = 0; j < 8; ++j)
        ((float4*)WloS)[tid + j * 256] = ((const float4*)Wlo)[tid + j * 256];
}

__device__ __forceinline__ void load_A_f32(const float* __restrict__ X, int M, int m0,
                                           half8 (&Ahi)[2][4], half8 (&Alo)[2][4]) {
    const int lane = threadIdx.x & 63;
    const int quad = lane >> 4, l16 = lane & 15;
#pragma unroll
    for (int r = 0; r < 2; ++r) {
        int row = m0 + r * 16 + l16;
        row = row < M ? row : (M - 1);
        const float* xr = X + (size_t)row * 128 + quad * 8;
#pragma unroll
        for (int s = 0; s < 4; ++s) {
            float4 a = ((const float4*)(xr + s * 32))[0];
            float4 b = ((const float4*)(xr + s * 32))[1];
            float v[8] = {a.x, a.y, a.z, a.w, b.x, b.y, b.z, b.w};
#pragma unroll
            for (int j = 0; j < 8; ++j) {
                _Float16 hi, lo;
                split_f16(v[j], hi, lo);
                Ahi[r][s][j] = hi;
                Alo[r][s][j] = lo;
            }
        }
    }
}

// Shared GEMM body: fp32 input, 3-term split-f16 MFMA. Output: PART-MAJOR
// fp16 table (4 slabs of [NS][32]); epilogue staged through SMEM, each wave
// writes 256B contiguous per slab (full-line coverage, no RMW).
__device__ __forceinline__ void gemm_body(const float* __restrict__ X,
                                          const _Float16* __restrict__ Whi,
                                          const _Float16* __restrict__ Wlo,
                                          __half* __restrict__ Y,
                                          int M, int NS, int blk, _Float16* SMEM) {
    _Float16* WhiS = SMEM;
    _Float16* WloS = SMEM + 16384;
    stage_frags(Whi, Wlo, WhiS, WloS);
    half8 Ahi[2][4], Alo[2][4];
    const int tid = threadIdx.x;
    const int lane = tid & 63, wave = tid >> 6;
    const int quad = lane >> 4, l16 = lane & 15;
    int m0 = blk * 128 + wave * 32;
    load_A_f32(X, M, m0, Ahi, Alo);
    __syncthreads();

    floatx4 acc[2][8];
#pragma unroll
    for (int r = 0; r < 2; ++r)
#pragma unroll
        for (int t = 0; t < 8; ++t) acc[r][t] = (floatx4){0.f, 0.f, 0.f, 0.f};

    const half8* WH = (const half8*)WhiS;
    const half8* WL = (const half8*)WloS;
#pragma unroll
    for (int s = 0; s < 4; ++s) {
#pragma unroll
        for (int t = 0; t < 8; ++t) {
            half8 bh = WH[(t * 4 + s) * 64 + lane];
            half8 bl = WL[(t * 4 + s) * 64 + lane];
#pragma unroll
            for (int r = 0; r < 2; ++r) {
                acc[r][t] = __builtin_amdgcn_mfma_f32_16x16x32_f16(Ahi[r][s], bh, acc[r][t], 0, 0, 0);
                acc[r][t] = __builtin_amdgcn_mfma_f32_16x16x32_f16(Alo[r][s], bh, acc[r][t], 0, 0, 0);
                acc[r][t] = __builtin_amdgcn_mfma_f32_16x16x32_f16(Ahi[r][s], bl, acc[r][t], 0, 0, 0);
            }
        }
    }

    __syncthreads();   // all W-fragment reads done; SMEM reusable
#pragma unroll
    for (int r = 0; r < 2; ++r)
#pragma unroll
        for (int t = 0; t < 8; ++t)
#pragma unroll
            for (int e = 0; e < 4; ++e)
                SMEM[(wave * 32 + r * 16 + quad * 4 + e) * 136 + t * 16 + l16] =
                    (_Float16)acc[r][t][e];
    __syncthreads();
    // partitioned store: part p = (tid&15)>>2 slab, 16B per lane
    const int c0 = (tid & 15) * 8;          // col in halves (0..120)
    const int p = c0 >> 5;                  // feature quarter
    const int po = c0 & 31;                 // offset within quarter (halves)
#pragma unroll
    for (int it = 0; it < 8; ++it) {
        int lr = it * 16 + (tid >> 4);
        int grow = blk * 128 + lr;
        if (grow < M)
            *(uint4*)(Y + ((size_t)p * NS + grow) * 32 + po) =
                *(const uint4*)(&SMEM[lr * 136 + c0]);
    }
}

// ---------------- K2: fused CSR build + layer-0 GEMM ------------------------
__global__ __launch_bounds__(256) void csrgemm_k(const unsigned* __restrict__ pk_arr,
                                                 const int* __restrict__ cursor,
                                                 int* __restrict__ row_ptr,
                                                 unsigned short* __restrict__ col_idx,
                                                 float* __restrict__ dinv,
                                                 const float* __restrict__ X,
                                                 const _Float16* __restrict__ Whi,
                                                 const _Float16* __restrict__ Wlo,
                                                 __half* __restrict__ hs,
                                                 int N, int E, int nbuk) {
    if ((int)blockIdx.x < nbuk) {
        csr_body(pk_arr, cursor, row_ptr, col_idx, dinv, N, E, nbuk, blockIdx.x);
        return;
    }
    __shared__ _Float16 SMEM[32768];
    gemm_body(X, Whi, Wlo, hs, N, N, blockIdx.x - nbuk, SMEM);
}

// ---------------- K4: standalone layer-1 GEMM -------------------------------
__global__ __launch_bounds__(256) void gemm1_k(const float* __restrict__ X,
                                               const _Float16* __restrict__ Whi,
                                               const _Float16* __restrict__ Wlo,
                                               __half* __restrict__ Y, int N) {
    __shared__ _Float16 SMEM[32768];
    gemm_body(X, Whi, Wlo, Y, N, N, blockIdx.x, SMEM);
}

// ---------------- K3/K5: XCD-local feature-split aggregate ------------------
// part = blockIdx.x & 3 -> via bid%8 XCD round-robin each XCD gathers from
// ONE contiguous [NS][32] fp16 slab (3.2MB, L2-resident). 8-lane groups, one
// node each, 8B/lane (64B row). Output standard layout: 32 fp32 per part =
// exactly one 128B line (no RMW, no cross-XCD partial-line hazard).
template <bool WEIGHTED>
__global__ __launch_bounds__(256, 8) void agg_split_k(const __half* __restrict__ tab,
                                                      const int* __restrict__ row_ptr,
                                                      const unsigned short* __restrict__ col_idx,
                                                      const float* __restrict__ dinv,
                                                      const float* __restrict__ bias,
                                                      float* __restrict__ outp,
                                                      int n, int NS) {
    const int tid = threadIdx.x;
    const int c8 = tid & 7;
    const int gw = tid & 56;           // 8-lane group base within wave
    const int part = blockIdx.x & 3;
    const int chunk = blockIdx.x >> 2;
    int i = chunk * 32 + (tid >> 3);
    if (i >= n) return;

    const __half* slab = tab + (size_t)part * NS * 32;
    const int ho = c8 * 4;                 // halves within the 32-half row

    float di = dinv[i];
    float acc[4];
    {
        uint2 raw = *(const uint2*)(slab + (size_t)i * 32 + ho);
        const __half2* hp = (const __half2*)&raw;
        float2 f0 = __half22float2(hp[0]);
        float2 f1 = __half22float2(hp[1]);
        if (WEIGHTED) {
            acc[0] = f0.x * di; acc[1] = f0.y * di;
            acc[2] = f1.x * di; acc[3] = f1.y * di;
        } else {
            acc[0] = f0.x; acc[1] = f0.y; acc[2] = f1.x; acc[3] = f1.y;
        }
    }

    int s = row_ptr[i];
    int cnt = row_ptr[i + 1] - s;

    for (int base = 0; base < cnt; base += 8) {
        int t = base + c8;
        int idx = (t < cnt) ? (int)col_idx[s + t] : 0;
        float dv = 0.f;
        if (WEIGHTED) dv = (t < cnt) ? dinv[idx] : 0.f;
        int lim = cnt - base; if (lim > 8) lim = 8;
        uint2 vv[8];
#pragma unroll
        for (int q = 0; q < 8; ++q) {
            int ia = __shfl(idx, gw + q);
            if (q < lim)
                vv[q] = *(const uint2*)(slab + (size_t)ia * 32 + ho);
        }
#pragma unroll
        for (int q = 0; q < 8; ++q) {
            if (q < lim) {
                const __half2* pq = (const __half2*)&vv[q];
                float2 f0 = __half22float2(pq[0]);
                float2 f1 = __half22float2(pq[1]);
                if (WEIGHTED) {
                    float wq = __shfl(dv, gw + q);
                    acc[0] = fmaf(f0.x, wq, acc[0]);
                    acc[1] = fmaf(f0.y, wq, acc[1]);
                    acc[2] = fmaf(f1.x, wq, acc[2]);
                    acc[3] = fmaf(f1.y, wq, acc[3]);
                } else {
                    acc[0] += f0.x; acc[1] += f0.y;
                    acc[2] += f1.x; acc[3] += f1.y;
                }
            }
        }
    }

    const int coff = part * 32 + ho;       // element offset in standard row
    float4 bq = *(const float4*)(bias + coff);
    float o0 = fmaf(acc[0], di, bq.x);
    float o1 = fmaf(acc[1], di, bq.y);
    float o2 = fmaf(acc[2], di, bq.z);
    float o3 = fmaf(acc[3], di, bq.w);
    if (WEIGHTED) {     // h1' = di * relu(.)  (pre-scaled for layer-1 GEMM)
        o0 = fmaxf(o0, 0.f) * di; o1 = fmaxf(o1, 0.f) * di;
        o2 = fmaxf(o2, 0.f) * di; o3 = fmaxf(o3, 0.f) * di;
    }
    *(float4*)(outp + (size_t)i * DFEAT + coff) = make_float4(o0, o1, o2, o3);
}

// ---------------- K6: heads (32 rows/block, LDS A-tiles, staged output) -----
#define LPH 136   // f16 LDS row stride
#define LPO 132   // f32 out-stage row stride
__global__ __launch_bounds__(256, 4) void heads_k(const float* __restrict__ X,
                                                  const _Float16* __restrict__ WvHi,
                                                  const _Float16* __restrict__ WvLo,
                                                  const _Float16* __restrict__ WtHi,
                                                  const _Float16* __restrict__ WtLo,
                                                  const float* __restrict__ bv,
                                                  const float* __restrict__ bt,
                                                  float* __restrict__ out_v,
                                                  float* __restrict__ out_t, int n) {
    __shared__ _Float16 AHi[32 * LPH];
    __shared__ _Float16 ALo[32 * LPH];
    __shared__ float OS[32 * LPO];
    const int tid = threadIdx.x;

    // load 32 rows of X, split to f16 hi/lo LDS tiles
    {
        int r = tid >> 3, c0 = (tid & 7) * 16;
        int grow = blockIdx.x * 32 + r;
        int gr = grow < n ? grow : (n > 0 ? n - 1 : 0);
#pragma unroll
        for (int q = 0; q < 4; ++q) {
            float4 v = *(const float4*)(X + (size_t)gr * DFEAT + c0 + q * 4);
            float vs[4] = {v.x, v.y, v.z, v.w};
#pragma unroll
            for (int e = 0; e < 4; ++e) {
                _Float16 hi, lo;
                split_f16(vs[e], hi, lo);
                AHi[r * LPH + c0 + q * 4 + e] = hi;
                ALo[r * LPH + c0 + q * 4 + e] = lo;
            }
        }
    }
    __syncthreads();

    const int lane = tid & 63, wave = tid >> 6;
    const int quad = lane >> 4, l16 = lane & 15;

#pragma unroll
    for (int hd = 0; hd < 2; ++hd) {
        const _Float16* Hi = hd ? WtHi : WvHi;
        const _Float16* Lo = hd ? WtLo : WvLo;
        const float* bb    = hd ? bt : bv;
        float* outp        = hd ? out_t : out_v;

        floatx4 acc[2][2];
#pragma unroll
        for (int tile = 0; tile < 2; ++tile) {
            acc[tile][0] = (floatx4){0.f, 0.f, 0.f, 0.f};
            acc[tile][1] = (floatx4){0.f, 0.f, 0.f, 0.f};
        }
#pragma unroll
        for (int s = 0; s < 4; ++s) {
#pragma unroll
            for (int tt = 0; tt < 2; ++tt) {
                size_t fi = ((size_t)(((wave * 2 + tt) * 4 + s) * 64 + lane)) * 8;
                half8 bh = *(const half8*)(Hi + fi);
                half8 bl = *(const half8*)(Lo + fi);
#pragma unroll
                for (int tile = 0; tile < 2; ++tile) {
                    int al = (tile * 16 + l16) * LPH + s * 32 + quad * 8;
                    half8 ahi = *(const half8*)(&AHi[al]);
                    half8 alo = *(const half8*)(&ALo[al]);
                    acc[tile][tt] = __builtin_amdgcn_mfma_f32_16x16x32_f16(ahi, bh, acc[tile][tt], 0, 0, 0);
                    acc[tile][tt] = __builtin_amdgcn_mfma_f32_16x16x32_f16(alo, bh, acc[tile][tt], 0, 0, 0);
                    acc[tile][tt] = __builtin_amdgcn_mfma_f32_16x16x32_f16(ahi, bl, acc[tile][tt], 0, 0, 0);
                }
            }
        }
        // stage into OS, then full 512B row stores
#pragma unroll
        for (int tile = 0; tile < 2; ++tile) {
#pragma unroll
            for (int tt = 0; tt < 2; ++tt) {
                int col = (wave * 2 + tt) * 16 + l16;
                float bc = bb[col];
#pragma unroll
                for (int e = 0; e < 4; ++e)
                    OS[(tile * 16 + quad * 4 + e) * LPO + col] =
                        fmaxf(acc[tile][tt][e] + bc, 0.f);
            }
        }
        __syncthreads();
        {
            int r = tid >> 3, c0 = (tid & 7) * 16;
            int grow = blockIdx.x * 32 + r;
            if (grow < n) {
#pragma unroll
                for (int q = 0; q < 4; ++q)
                    *(float4*)(outp + (size_t)grow * DFEAT + c0 + q * 4) =
                        *(const float4*)(&OS[r * LPO + c0 + q * 4]);
            }
        }
        __syncthreads();
    }
}

// ---------------------------------------------------------------------------

static inline size_t align_up(size_t x, size_t a) { return (x + a - 1) & ~(a - 1); }

extern "C" void kernel_launch(void* const* d_in, const int* in_sizes, int n_in,
                              void* d_out, int out_size, void* d_ws, size_t ws_size,
                              hipStream_t stream) {
    const float* x  = (const float*)d_in[0];
    const int*   ei = (const int*)d_in[1];
    const float* W0 = (const float*)d_in[2];
    const float* b0 = (const float*)d_in[3];
    const float* W1 = (const float*)d_in[4];
    const float* b1 = (const float*)d_in[5];
    const float* Wv = (const float*)d_in[6];
    const float* bv = (const float*)d_in[7];
    const float* Wt = (const float*)d_in[8];
    const float* bt = (const float*)d_in[9];

    const int N = in_sizes[0] / DFEAT;
    const int E = in_sizes[1] / 2;
    const int* src = ei;
    const int* dst = ei + E;
    const int nbuk = (N + 255) >> BSH;
    const int npb  = (E + BKE - 1) / BKE;
    const int gb   = (N + 127) / 128;
    const int nchk = (N + 31) / 32;

    // workspace carve-up
    char* w = (char*)d_ws;
    int* cursor      = (int*)w; w += align_up((size_t)256 * 4, 256);
    unsigned* pk_arr = (unsigned*)w; w += align_up((size_t)nbuk * SLABCAP * 4, 256);
    int* row_ptr     = (int*)w; w += align_up((size_t)(N + 1) * 4, 256);
    unsigned short* col_idx = (unsigned short*)w; w += align_up((size_t)E * 2, 256);
    float* dinv      = (float*)w; w += align_up((size_t)N * 4, 256);
    _Float16* whi_all = (_Float16*)w; w += align_up(4 * 16384 * 2, 256);
    _Float16* wlo_all = (_Float16*)w; w += align_up(4 * 16384 * 2, 256);
    __half* hs       = (__half*)w; w += align_up((size_t)N * DFEAT * 2, 256);
    __half* hs2      = (__half*)w; w += align_up((size_t)N * DFEAT * 2, 256);
    float* h1p       = (float*)w; w += align_up((size_t)N * DFEAT * 4, 256);

    _Float16* w0hi = whi_all;            _Float16* w0lo = wlo_all;
    _Float16* w1hi = whi_all + 16384;    _Float16* w1lo = wlo_all + 16384;
    _Float16* wvhi = whi_all + 2*16384;  _Float16* wvlo = wlo_all + 2*16384;
    _Float16* wthi = whi_all + 3*16384;  _Float16* wtlo = wlo_all + 3*16384;

    float* out_h = (float*)d_out;
    float* out_v = out_h + (size_t)N * DFEAT;
    float* out_t = out_h + 2 * (size_t)N * DFEAT;

    hipMemsetAsync(cursor, 0, 256 * 4, stream);

    // K1: W prep + slab partition
    prep_part_k<<<256 + npb, 256, 0, stream>>>(src, dst, cursor, pk_arr,
                                               W0, W1, Wv, Wt, whi_all, wlo_all,
                                               E, nbuk);
    // K2: CSR build + layer-0 GEMM (co-resident) -> hs (part-major fp16)
    csrgemm_k<<<nbuk + gb, 256, 0, stream>>>(pk_arr, cursor, row_ptr, col_idx,
                                             dinv, x, w0hi, w0lo, hs, N, E, nbuk);
    // K3: weighted agg, XCD-local contiguous slabs -> h1p (fp32 standard)
    agg_split_k<true><<<nchk * 4, 256, 0, stream>>>(hs, row_ptr, col_idx, dinv,
                                                    b0, h1p, N, N);
    // K4: layer-1 GEMM -> hs2 (part-major fp16, rows pre-scaled via h1p)
    gemm1_k<<<gb, 256, 0, stream>>>(h1p, w1hi, w1lo, hs2, N);
    // K5: plain agg, XCD-local contiguous slabs -> out_h (fp32 standard)
    agg_split_k<false><<<nchk * 4, 256, 0, stream>>>(hs2, row_ptr, col_idx, dinv,
                                                     b1, out_h, N, N);
    // K6: heads from out_h
    heads_k<<<nchk, 256, 0, stream>>>(out_h, wvhi, wvlo, wthi, wtlo, bv, bt,
                                      out_v, out_t, N);
}

// Round 13
// 209.968 us; speedup vs baseline: 1.2602x; 1.1585x over previous
//
#include <hip/hip_runtime.h>
#include <hip/hip_fp16.h>
#include <math.h>

// ---------------------------------------------------------------------------
// GCN 2-layer + two heads, fp32 in/out, MI355X.
//   R18 = R15 (session best, 212.1us): 16-node fused agg blocks, lean VGPR,
//   5 dispatches, FULL-LINE epilogue stores staged through LDS.
//   Settled findings:
//   - agg gather is pinned at ~3.1 TB/s L2-miss/L3 service rate (table
//     12.8MB > 4MB per-XCD L2; random neighbors). XCD-local split (R16/R17)
//     fixes the gather but its de-fusion cost (h1p round trip + 2 extra
//     dispatches ~30us) exceeds the gain (~25us).
//   - partial-line epilogue stores cause L2 write-allocate RMW (R13/R14);
//     full-line staged stores are mandatory.
//   - nt stores amplify partial-line writes 2x (R13). VGPR<=64 keeps agg
//     occupancy at 8 waves/SIMD (R11).
// ---------------------------------------------------------------------------

#define DFEAT 128
#define BSH 8            // bucket = dst >> 8 (256 nodes/bucket)
#define BKE 4096         // edges per partition block
#define SLABCAP 4608     // bucket slab capacity: mean 4096 + 8 sigma

using half8   = __attribute__((ext_vector_type(8))) _Float16;
using floatx4 = __attribute__((ext_vector_type(4))) float;

__device__ __forceinline__ void split_f16(float x, _Float16& hi, _Float16& lo) {
    _Float16 h = (_Float16)x;
    hi = h;
    lo = (_Float16)(x - (float)h);
}

// ---------------- K1: W pre-split to f16 frags  +  slab partition -----------
__global__ __launch_bounds__(256) void prep_part_k(const int* __restrict__ src,
                                                   const int* __restrict__ dst,
                                                   int* __restrict__ cursor,
                                                   unsigned* __restrict__ pk_out,
                                                   const float* __restrict__ W0,
                                                   const float* __restrict__ W1,
                                                   const float* __restrict__ W2,
                                                   const float* __restrict__ W3,
                                                   _Float16* __restrict__ hi_all,
                                                   _Float16* __restrict__ lo_all,
                                                   int E, int nbuk) {
    int tid = threadIdx.x;
    if (blockIdx.x < 256) {
        int pb = blockIdx.x;
        int b = pb >> 6;
        const float* W = (b == 0) ? W0 : (b == 1) ? W1 : (b == 2) ? W2 : W3;
        _Float16* hi = hi_all + (size_t)b * 16384;
        _Float16* lo = lo_all + (size_t)b * 16384;
        int i = (pb & 63) * 256 + tid;
        int j = i & 7;
        int lane = (i >> 3) & 63;
        int ts = i >> 9;
        int s = ts & 3, t = ts >> 2;
        int k = s * 32 + (lane >> 4) * 8 + j;
        int n = t * 16 + (lane & 15);
        split_f16(W[k * 128 + n], hi[i], lo[i]);
        return;
    }

    // ---- partition body ----
    __shared__ int h[256];
    __shared__ int base[256];
    h[tid] = 0;
    __syncthreads();
    int B = blockIdx.x - 256;
    int e0 = B * BKE;

    unsigned pk[16];
    unsigned short rk[16];
    unsigned char bk[16];
    int m = 0;
#pragma unroll
    for (int it = 0; it < 4; ++it) {
        int e = e0 + it * 1024 + tid * 4;
        if (e + 3 < E) {
            int4 d4 = *(const int4*)(dst + e);
            int4 s4 = *(const int4*)(src + e);
            int dd[4] = {d4.x, d4.y, d4.z, d4.w};
            int ss[4] = {s4.x, s4.y, s4.z, s4.w};
#pragma unroll
            for (int k = 0; k < 4; ++k) {
                int b = dd[k] >> BSH;
                pk[m] = ((unsigned)dd[k] << 16) | (unsigned)ss[k];
                rk[m] = (unsigned short)atomicAdd(&h[b], 1);
                bk[m] = (unsigned char)b;
                ++m;
            }
        } else {
            for (int k = 0; k < 4; ++k) {
                if (e + k < E) {
                    int d = dst[e + k], sv = src[e + k];
                    int b = d >> BSH;
                    pk[m] = ((unsigned)d << 16) | (unsigned)sv;
                    rk[m] = (unsigned short)atomicAdd(&h[b], 1);
                    bk[m] = (unsigned char)b;
                    ++m;
                }
            }
        }
    }
    __syncthreads();
    if (tid < nbuk && h[tid]) base[tid] = tid * SLABCAP + atomicAdd(&cursor[tid], h[tid]);
    __syncthreads();
    for (int j2 = 0; j2 < m; ++j2)
        pk_out[base[bk[j2]] + (int)rk[j2]] = pk[j2];
}

// ---------------- CSR build from slabs (counts live in cursor) --------------
__device__ __forceinline__ void csr_body(const unsigned* __restrict__ pk_arr,
                                         const int* __restrict__ cursor,
                                         int* __restrict__ row_ptr,
                                         unsigned short* __restrict__ col_idx,
                                         float* __restrict__ dinv,
                                         int N, int E, int nbuk, int b) {
    __shared__ int hcnt[256];
    __shared__ int esc[256];
    __shared__ int sx[256];
    int tid = threadIdx.x;

    int v = (tid < nbuk) ? cursor[tid] : 0;
    sx[tid] = v;
    __syncthreads();
    int x = v;
    for (int o = 1; o < 256; o <<= 1) {
        int y = (tid >= o) ? sx[tid - o] : 0;
        __syncthreads();
        x += y;
        sx[tid] = x;
        __syncthreads();
    }
    int s0 = (b > 0) ? sx[b - 1] : 0;
    int cnt = sx[b] - s0;
    __syncthreads();

    hcnt[tid] = 0;
    __syncthreads();

    const unsigned* slab = pk_arr + (size_t)b * SLABCAP;
    unsigned p[20];
    unsigned short r[20];
    int m = 0;
    for (int i = tid; i < cnt; i += 256) {
        unsigned pp = slab[i];
        int d = (pp >> 16) & 255;
        r[m] = (unsigned short)atomicAdd(&hcnt[d], 1);
        p[m] = pp;
        ++m;
    }
    __syncthreads();

    int hv = hcnt[tid];
    esc[tid] = hv;
    __syncthreads();
    int hx = hv;
    for (int o = 1; o < 256; o <<= 1) {
        int y = (tid >= o) ? esc[tid - o] : 0;
        __syncthreads();
        hx += y;
        esc[tid] = hx;
        __syncthreads();
    }
    int excl = hx - hv;
    __syncthreads();
    esc[tid] = excl;
    __syncthreads();

    int node = (b << BSH) + tid;
    if (node < N) {
        row_ptr[node] = s0 + excl;
        dinv[node] = rsqrtf((float)(hv + 1));   // +1 self loop
    }
    if (node == N) row_ptr[N] = E;

    for (int j = 0; j < m; ++j) {
        int d = (p[j] >> 16) & 255;
        col_idx[s0 + esc[d] + (int)r[j]] = (unsigned short)(p[j] & 0xFFFFu);
    }
}

// ---------------- GEMM pieces (split-f16 MFMA, prepped fragments) -----------
__device__ __forceinline__ void stage_frags(const _Float16* __restrict__ Whi,
                                            const _Float16* __restrict__ Wlo,
                                            _Float16* __restrict__ WhiS,
                                            _Float16* __restrict__ WloS) {
    const int tid = threadIdx.x;
#pragma unroll
    for (int j = 0; j < 8; ++j)
        ((float4*)WhiS)[tid + j * 256] = ((const float4*)Whi)[tid + j * 256];
#pragma unroll
    for (int j = 0; j < 8; ++j)
        ((float4*)WloS)[tid + j * 256] = ((const float4*)Wlo)[tid + j * 256];
}

template <typename InT>
__device__ __forceinline__ void load_A(const InT* __restrict__ X, int M, int m0,
                                       half8 (&Ahi)[2][4], half8 (&Alo)[2][4]) {
    const int lane = threadIdx.x & 63;
    const int quad = lane >> 4, l16 = lane & 15;
#pragma unroll
    for (int r = 0; r < 2; ++r) {
        int row = m0 + r * 16 + l16;
        row = row < M ? row : (M - 1);
        const InT* xr = X + (size_t)row * 128 + quad * 8;
#pragma unroll
        for (int s = 0; s < 4; ++s) {
            if constexpr (sizeof(InT) == 2) {
                Ahi[r][s] = *(const half8*)(xr + s * 32);   // exact
            } else {
                float4 a = ((const float4*)(xr + s * 32))[0];
                float4 b = ((const float4*)(xr + s * 32))[1];
                float v[8] = {a.x, a.y, a.z, a.w, b.x, b.y, b.z, b.w};
#pragma unroll
                for (int j = 0; j < 8; ++j) {
                    _Float16 hi, lo;
                    split_f16(v[j], hi, lo);
                    Ahi[r][s][j] = hi;
                    Alo[r][s][j] = lo;
                }
            }
        }
    }
}

// ---------------- K2: fused CSR build + layer-0 GEMM ------------------------
// GEMM epilogue: acc -> LDS f16 tile [128][136] -> full 256B row stores
// (uint4 per lane) -> no partial-line write-allocate RMW on hs.
__global__ __launch_bounds__(256) void csrgemm_k(const unsigned* __restrict__ pk_arr,
                                                 const int* __restrict__ cursor,
                                                 int* __restrict__ row_ptr,
                                                 unsigned short* __restrict__ col_idx,
                                                 float* __restrict__ dinv,
                                                 const float* __restrict__ X,
                                                 const _Float16* __restrict__ Whi,
                                                 const _Float16* __restrict__ Wlo,
                                                 __half* __restrict__ hs,
                                                 int N, int E, int nbuk) {
    if ((int)blockIdx.x < nbuk) {
        csr_body(pk_arr, cursor, row_ptr, col_idx, dinv, N, E, nbuk, blockIdx.x);
        return;
    }
    __shared__ _Float16 SMEM[32768];   // Whi|Wlo staging, reused for epilogue
    _Float16* WhiS = SMEM;
    _Float16* WloS = SMEM + 16384;
    stage_frags(Whi, Wlo, WhiS, WloS);
    half8 Ahi[2][4], Alo[2][4];
    const int tid = threadIdx.x;
    const int lane = tid & 63, wave = tid >> 6;
    const int quad = lane >> 4, l16 = lane & 15;
    int blk = blockIdx.x - nbuk;
    int m0 = blk * 128 + wave * 32;
    load_A<float>(X, N, m0, Ahi, Alo);
    __syncthreads();

    floatx4 acc[2][8];
#pragma unroll
    for (int r = 0; r < 2; ++r)
#pragma unroll
        for (int t = 0; t < 8; ++t) acc[r][t] = (floatx4){0.f, 0.f, 0.f, 0.f};

    const half8* WH = (const half8*)WhiS;
    const half8* WL = (const half8*)WloS;
#pragma unroll
    for (int s = 0; s < 4; ++s) {
#pragma unroll
        for (int t = 0; t < 8; ++t) {
            half8 bh = WH[(t * 4 + s) * 64 + lane];
            half8 bl = WL[(t * 4 + s) * 64 + lane];
#pragma unroll
            for (int r = 0; r < 2; ++r) {
                acc[r][t] = __builtin_amdgcn_mfma_f32_16x16x32_f16(Ahi[r][s], bh, acc[r][t], 0, 0, 0);
                acc[r][t] = __builtin_amdgcn_mfma_f32_16x16x32_f16(Alo[r][s], bh, acc[r][t], 0, 0, 0);
                acc[r][t] = __builtin_amdgcn_mfma_f32_16x16x32_f16(Ahi[r][s], bl, acc[r][t], 0, 0, 0);
            }
        }
    }

    __syncthreads();   // all W-fragment reads done; SMEM reusable
#pragma unroll
    for (int r = 0; r < 2; ++r)
#pragma unroll
        for (int t = 0; t < 8; ++t)
#pragma unroll
            for (int e = 0; e < 4; ++e)
                SMEM[(wave * 32 + r * 16 + quad * 4 + e) * 136 + t * 16 + l16] =
                    (_Float16)acc[r][t][e];
    __syncthreads();
#pragma unroll
    for (int it = 0; it < 8; ++it) {
        int lr = it * 16 + (tid >> 4);
        int grow = blk * 128 + lr;
        if (grow < N)
            *(uint4*)(hs + (size_t)grow * 128 + (tid & 15) * 8) =
                *(const uint4*)(&SMEM[lr * 136 + (tid & 15) * 8]);
    }
}

// ---------------- K3: fused weighted agg + layer-1 GEMM ---------------------
// Block owns 16 nodes (one per 16-lane group). Phase 1: weighted aggregate
// (8-deep batches, consume-time weight shfl, epilogue bias) -> padded LDS
// f16 tile. Phase 2: 2-term f16 GEMM (B streamed from L2), result staged back
// into the LDS tile -> full 256B row stores.
#define LP16 136   // f16 elems per LDS row (272B stride -> 2-way banks)
__global__ __launch_bounds__(256, 8) void agg0gemm1_k(const __half* __restrict__ hs,
                                                      const int* __restrict__ row_ptr,
                                                      const unsigned short* __restrict__ col_idx,
                                                      const float* __restrict__ dinv,
                                                      const float* __restrict__ bias,
                                                      const _Float16* __restrict__ W1hi,
                                                      const _Float16* __restrict__ W1lo,
                                                      __half* __restrict__ out_hs, int n) {
    __shared__ _Float16 A[16 * LP16];
    const int tid = threadIdx.x;
    const int c = tid & 15;
    const int g = tid >> 4;
    const int gbase = tid & 48;

    int i = blockIdx.x * 16 + g;

    if (i < n) {
        float di = dinv[i];
        float acc[8];
        {
            uint4 raw = ((const uint4*)(hs + (size_t)i * DFEAT))[c];
            const __half2* hp = (const __half2*)&raw;
#pragma unroll
            for (int k = 0; k < 4; ++k) {
                float2 f = __half22float2(hp[k]);
                acc[2 * k] = f.x * di; acc[2 * k + 1] = f.y * di;
            }
        }
        int s = row_ptr[i];
        int cnt = row_ptr[i + 1] - s;

        for (int base = 0; base < cnt; base += 16) {
            int t = base + c;
            int idx = (t < cnt) ? (int)col_idx[s + t] : 0;
            float dv = (t < cnt) ? dinv[idx] : 0.f;
            int lim = cnt - base; if (lim > 16) lim = 16;
#pragma unroll
            for (int h = 0; h < 2; ++h) {
                int l0 = h * 8;
                if (l0 < lim) {
                    uint4 vv[8];
#pragma unroll
                    for (int q = 0; q < 8; ++q) {
                        int ia = __shfl(idx, gbase + l0 + q);
                        if (l0 + q < lim)
                            vv[q] = ((const uint4*)(hs + (size_t)ia * DFEAT))[c];
                    }
#pragma unroll
                    for (int q = 0; q < 8; ++q) {
                        if (l0 + q < lim) {
                            float wq = __shfl(dv, gbase + l0 + q);
                            const __half2* pq = (const __half2*)&vv[q];
#pragma unroll
                            for (int k = 0; k < 4; ++k) {
                                float2 f = __half22float2(pq[k]);
                                acc[2 * k]     = fmaf(f.x, wq, acc[2 * k]);
                                acc[2 * k + 1] = fmaf(f.y, wq, acc[2 * k + 1]);
                            }
                        }
                    }
                }
            }
        }

        float4 b0 = ((const float4*)bias)[c * 2];
        float4 b1 = ((const float4*)bias)[c * 2 + 1];
        float o[8];
        o[0] = fmaf(acc[0], di, b0.x); o[1] = fmaf(acc[1], di, b0.y);
        o[2] = fmaf(acc[2], di, b0.z); o[3] = fmaf(acc[3], di, b0.w);
        o[4] = fmaf(acc[4], di, b1.x); o[5] = fmaf(acc[5], di, b1.y);
        o[6] = fmaf(acc[6], di, b1.z); o[7] = fmaf(acc[7], di, b1.w);
        _Float16 hv[8];
#pragma unroll
        for (int k = 0; k < 8; ++k) hv[k] = (_Float16)(fmaxf(o[k], 0.f) * di);
        *(uint4*)(&A[g * LP16 + c * 8]) = *(uint4*)hv;
    } else {
        uint4 z = {0u, 0u, 0u, 0u};
        *(uint4*)(&A[g * LP16 + c * 8]) = z;
    }

    __syncthreads();

    // ---- phase 2: GEMM (each wave: 2 column blocks of 16) ----
    const int lane = tid & 63, wave = tid >> 6;
    const int quad = lane >> 4, l16 = lane & 15;
    half8 a[4];
#pragma unroll
    for (int s = 0; s < 4; ++s)
        a[s] = *(const half8*)(&A[l16 * LP16 + s * 32 + quad * 8]);

    floatx4 acc2[2];
    acc2[0] = (floatx4){0.f, 0.f, 0.f, 0.f};
    acc2[1] = (floatx4){0.f, 0.f, 0.f, 0.f};
#pragma unroll
    for (int s = 0; s < 4; ++s) {
#pragma unroll
        for (int tt = 0; tt < 2; ++tt) {
            int t = wave * 2 + tt;
            half8 bh = *(const half8*)(W1hi + ((size_t)((t * 4 + s) * 64 + lane)) * 8);
            half8 bl = *(const half8*)(W1lo + ((size_t)((t * 4 + s) * 64 + lane)) * 8);
            acc2[tt] = __builtin_amdgcn_mfma_f32_16x16x32_f16(a[s], bh, acc2[tt], 0, 0, 0);
            acc2[tt] = __builtin_amdgcn_mfma_f32_16x16x32_f16(a[s], bl, acc2[tt], 0, 0, 0);
        }
    }

    __syncthreads();   // all A reads done; stage result into A
#pragma unroll
    for (int tt = 0; tt < 2; ++tt) {
        int col = (wave * 2 + tt) * 16 + l16;
#pragma unroll
        for (int e = 0; e < 4; ++e)
            A[(quad * 4 + e) * LP16 + col] = (_Float16)acc2[tt][e];
    }
    __syncthreads();
    if (i < n)
        *(uint4*)(out_hs + (size_t)i * DFEAT + c * 8) =
            *(const uint4*)(&A[g * LP16 + c * 8]);
}

// ---------------- K4: fused plain agg + heads -------------------------------
// Phase 1: unweighted aggregate, write out_h (full-line float4 pairs) and
// stash rows in fp32 LDS tile. Phase 2: heads sequential; each head's result
// staged back through the LDS tile -> full 512B row stores (no RMW).
#define LP32 132   // f32 elems per LDS row (528B stride -> 2-way banks)
__global__ __launch_bounds__(256, 8) void agg1heads_k(const __half* __restrict__ hs,
                                                      const int* __restrict__ row_ptr,
                                                      const unsigned short* __restrict__ col_idx,
                                                      const float* __restrict__ dinv,
                                                      const float* __restrict__ bias,
                                                      const _Float16* __restrict__ WvHi,
                                                      const _Float16* __restrict__ WvLo,
                                                      const _Float16* __restrict__ WtHi,
                                                      const _Float16* __restrict__ WtLo,
                                                      const float* __restrict__ bv,
                                                      const float* __restrict__ bt,
                                                      float* __restrict__ out_h,
                                                      float* __restrict__ out_v,
                                                      float* __restrict__ out_t, int n) {
    __shared__ float Af[16 * LP32];
    const int tid = threadIdx.x;
    const int c = tid & 15;
    const int g = tid >> 4;
    const int gbase = tid & 48;

    int i = blockIdx.x * 16 + g;

    if (i < n) {
        float acc[8];
        {
            uint4 raw = ((const uint4*)(hs + (size_t)i * DFEAT))[c];
            const __half2* hp = (const __half2*)&raw;
#pragma unroll
            for (int k = 0; k < 4; ++k) {
                float2 f = __half22float2(hp[k]);
                acc[2 * k] = f.x; acc[2 * k + 1] = f.y;
            }
        }
        int s = row_ptr[i];
        int cnt = row_ptr[i + 1] - s;

        for (int base = 0; base < cnt; base += 16) {
            int t = base + c;
            int idx = (t < cnt) ? (int)col_idx[s + t] : 0;
            int lim = cnt - base; if (lim > 16) lim = 16;
#pragma unroll
            for (int h = 0; h < 2; ++h) {
                int l0 = h * 8;
                if (l0 < lim) {
                    uint4 vv[8];
#pragma unroll
                    for (int q = 0; q < 8; ++q) {
                        int ia = __shfl(idx, gbase + l0 + q);
                        if (l0 + q < lim)
                            vv[q] = ((const uint4*)(hs + (size_t)ia * DFEAT))[c];
                    }
#pragma unroll
                    for (int q = 0; q < 8; ++q) {
                        if (l0 + q < lim) {
                            const __half2* pq = (const __half2*)&vv[q];
#pragma unroll
                            for (int k = 0; k < 4; ++k) {
                                float2 f = __half22float2(pq[k]);
                                acc[2 * k]     += f.x;
                                acc[2 * k + 1] += f.y;
                            }
                        }
                    }
                }
            }
        }

        float di = dinv[i];
        float4 b0 = ((const float4*)bias)[c * 2];
        float4 b1 = ((const float4*)bias)[c * 2 + 1];
        float o[8];
        o[0] = fmaf(acc[0], di, b0.x); o[1] = fmaf(acc[1], di, b0.y);
        o[2] = fmaf(acc[2], di, b0.z); o[3] = fmaf(acc[3], di, b0.w);
        o[4] = fmaf(acc[4], di, b1.x); o[5] = fmaf(acc[5], di, b1.y);
        o[6] = fmaf(acc[6], di, b1.z); o[7] = fmaf(acc[7], di, b1.w);
        float4 w0 = make_float4(o[0], o[1], o[2], o[3]);
        float4 w1 = make_float4(o[4], o[5], o[6], o[7]);
        ((float4*)(out_h + (size_t)i * DFEAT))[c * 2] = w0;
        ((float4*)(out_h + (size_t)i * DFEAT))[c * 2 + 1] = w1;
        *(float4*)(&Af[g * LP32 + c * 8]) = w0;
        *(float4*)(&Af[g * LP32 + c * 8 + 4]) = w1;
    } else {
        float4 z = make_float4(0.f, 0.f, 0.f, 0.f);
        *(float4*)(&Af[g * LP32 + c * 8]) = z;
        *(float4*)(&Af[g * LP32 + c * 8 + 4]) = z;
    }

    __syncthreads();

    // ---- phase 2: head GEMMs, sequential (V then T) ----
    const int lane = tid & 63, wave = tid >> 6;
    const int quad = lane >> 4, l16 = lane & 15;
    half8 ahi[4], alo[4];
#pragma unroll
    for (int s = 0; s < 4; ++s) {
        float4 fa = *(const float4*)(&Af[l16 * LP32 + s * 32 + quad * 8]);
        float4 fb = *(const float4*)(&Af[l16 * LP32 + s * 32 + quad * 8 + 4]);
        float v[8] = {fa.x, fa.y, fa.z, fa.w, fb.x, fb.y, fb.z, fb.w};
#pragma unroll
        for (int j = 0; j < 8; ++j) {
            _Float16 hi, lo;
            split_f16(v[j], hi, lo);
            ahi[s][j] = hi;
            alo[s][j] = lo;
        }
    }
    __syncthreads();   // A-fragment reads done; Af reusable as output stage

#pragma unroll
    for (int hd = 0; hd < 2; ++hd) {
        const _Float16* Hi = hd ? WtHi : WvHi;
        const _Float16* Lo = hd ? WtLo : WvLo;
        const float* bb    = hd ? bt : bv;
        float* outp        = hd ? out_t : out_v;

        floatx4 acc[2];
        acc[0] = (floatx4){0.f, 0.f, 0.f, 0.f};
        acc[1] = (floatx4){0.f, 0.f, 0.f, 0.f};
#pragma unroll
        for (int s = 0; s < 4; ++s) {
#pragma unroll
            for (int tt = 0; tt < 2; ++tt) {
                size_t fi = ((size_t)(((wave * 2 + tt) * 4 + s) * 64 + lane)) * 8;
                half8 bh = *(const half8*)(Hi + fi);
                half8 bl = *(const half8*)(Lo + fi);
                acc[tt] = __builtin_amdgcn_mfma_f32_16x16x32_f16(ahi[s], bh, acc[tt], 0, 0, 0);
                acc[tt] = __builtin_amdgcn_mfma_f32_16x16x32_f16(alo[s], bh, acc[tt], 0, 0, 0);
                acc[tt] = __builtin_amdgcn_mfma_f32_16x16x32_f16(ahi[s], bl, acc[tt], 0, 0, 0);
            }
        }
        // stage into Af, then full-line row stores
#pragma unroll
        for (int tt = 0; tt < 2; ++tt) {
            int col = (wave * 2 + tt) * 16 + l16;
            float bc = bb[col];
#pragma unroll
            for (int e = 0; e < 4; ++e)
                Af[(quad * 4 + e) * LP32 + col] = fmaxf(acc[tt][e] + bc, 0.f);
        }
        __syncthreads();
        if (i < n) {
            *(float4*)(outp + (size_t)i * DFEAT + c * 8) =
                *(const float4*)(&Af[g * LP32 + c * 8]);
            *(float4*)(outp + (size_t)i * DFEAT + c * 8 + 4) =
                *(const float4*)(&Af[g * LP32 + c * 8 + 4]);
        }
        __syncthreads();
    }
}

// ---------------------------------------------------------------------------

static inline size_t align_up(size_t x, size_t a) { return (x + a - 1) & ~(a - 1); }

extern "C" void kernel_launch(void* const* d_in, const int* in_sizes, int n_in,
                              void* d_out, int out_size, void* d_ws, size_t ws_size,
                              hipStream_t stream) {
    const float* x  = (const float*)d_in[0];
    const int*   ei = (const int*)d_in[1];
    const float* W0 = (const float*)d_in[2];
    const float* b0 = (const float*)d_in[3];
    const float* W1 = (const float*)d_in[4];
    const float* b1 = (const float*)d_in[5];
    const float* Wv = (const float*)d_in[6];
    const float* bv = (const float*)d_in[7];
    const float* Wt = (const float*)d_in[8];
    const float* bt = (const float*)d_in[9];

    const int N = in_sizes[0] / DFEAT;
    const int E = in_sizes[1] / 2;
    const int* src = ei;
    const int* dst = ei + E;
    const int nbuk = (N + 255) >> BSH;
    const int npb  = (E + BKE - 1) / BKE;
    const int gb   = (N + 127) / 128;
    const int fusB = (N + 15) / 16;

    // workspace carve-up
    char* w = (char*)d_ws;
    int* cursor      = (int*)w; w += align_up((size_t)256 * 4, 256);
    unsigned* pk_arr = (unsigned*)w; w += align_up((size_t)nbuk * SLABCAP * 4, 256);
    int* row_ptr     = (int*)w; w += align_up((size_t)(N + 1) * 4, 256);
    unsigned short* col_idx = (unsigned short*)w; w += align_up((size_t)E * 2, 256);
    float* dinv      = (float*)w; w += align_up((size_t)N * 4, 256);
    _Float16* whi_all = (_Float16*)w; w += align_up(4 * 16384 * 2, 256);
    _Float16* wlo_all = (_Float16*)w; w += align_up(4 * 16384 * 2, 256);
    __half* hs       = (__half*)w; w += align_up((size_t)N * DFEAT * 2, 256);
    __half* hs2      = (__half*)w; w += align_up((size_t)N * DFEAT * 2, 256);

    _Float16* w0hi = whi_all;            _Float16* w0lo = wlo_all;
    _Float16* w1hi = whi_all + 16384;    _Float16* w1lo = wlo_all + 16384;
    _Float16* wvhi = whi_all + 2*16384;  _Float16* wvlo = wlo_all + 2*16384;
    _Float16* wthi = whi_all + 3*16384;  _Float16* wtlo = wlo_all + 3*16384;

    float* out_h = (float*)d_out;
    float* out_v = out_h + (size_t)N * DFEAT;
    float* out_t = out_h + 2 * (size_t)N * DFEAT;

    hipMemsetAsync(cursor, 0, 256 * 4, stream);

    // K1: W prep + slab partition
    prep_part_k<<<256 + npb, 256, 0, stream>>>(src, dst, cursor, pk_arr,
                                               W0, W1, Wv, Wt, whi_all, wlo_all,
                                               E, nbuk);
    // K2: CSR build + unscaled layer-0 GEMM (co-resident)
    csrgemm_k<<<nbuk + gb, 256, 0, stream>>>(pk_arr, cursor, row_ptr, col_idx,
                                             dinv, x, w0hi, w0lo, hs, N, E, nbuk);
    // K3: weighted agg + layer-1 GEMM fused -> hs2
    agg0gemm1_k<<<fusB, 256, 0, stream>>>(hs, row_ptr, col_idx, dinv, b0,
                                          w1hi, w1lo, hs2, N);
    // K4: plain agg + both heads fused -> out_h, out_v, out_t
    agg1heads_k<<<fusB, 256, 0, stream>>>(hs2, row_ptr, col_idx, dinv, b1,
                                          wvhi, wvlo, wthi, wtlo, bv, bt,
                                          out_h, out_v, out_t, N);
}